// Round 1
// baseline (736.448 us; speedup 1.0000x reference)
//
#include <hip/hip_runtime.h>
#include <cstdint>

#define LRELU_SLOPE 0.1f
#define BN_NB 256  // blocks in batchnorm partial-reduction

// ---------------------------------------------------------------------------
// Gather-GEMM sparse conv: out[r, c] = sum_k sum_ci fin[nmap[r,k], ci] * W[k,ci,c] + bias[c]
// Sentinel nmap entries (== nin) contribute zero.
// If AFF: gathered features are transformed v = v*affA[ci] + affB[ci] (valid rows only)
//         -> fuses BatchNorm+scale into the conv3 gather.
// Block: 256 threads. 64 output rows/block. Thread (tx=tid&15, ty=tid>>4)
// computes rows ty*4..ty*4+3  x  channels tx*4..tx*4+3 (4x4 register tile).
// ---------------------------------------------------------------------------
template<int K, int CIN, bool LEAKY, bool AFF>
__global__ __launch_bounds__(256) void sconv_kernel(
    const float* __restrict__ fin, int nin,
    const int* __restrict__ nmap,
    const float* __restrict__ W,     // [K][CIN][64]
    const float* __restrict__ bias,  // [64]
    const float* __restrict__ affA,  // [64] or null
    const float* __restrict__ affB,  // [64] or null
    float* __restrict__ fout, int nout)
{
    constexpr int TM = 64;
    constexpr int STRIDE = CIN + 4;   // padded floats per LDS row (x4 bytes stays 16B aligned)
    constexpr int QPR = CIN / 4;      // float4 per feature row
    __shared__ float lds[TM * STRIDE];

    const int tid = threadIdx.x;
    const int tx = tid & 15;          // channel group -> channels tx*4 .. tx*4+3
    const int ty = tid >> 4;          // row group    -> rows ty*4 .. ty*4+3
    const int base = blockIdx.x * TM;

    float acc[4][4];
#pragma unroll
    for (int i = 0; i < 4; ++i)
#pragma unroll
        for (int j = 0; j < 4; ++j) acc[i][j] = 0.f;

    for (int k = 0; k < K; ++k) {
        __syncthreads();
        // ---- stage 64 gathered feature rows for tap k into LDS ----
#pragma unroll
        for (int e = tid; e < TM * QPR; e += 256) {
            const int row = e / QPR;
            const int q = e - row * QPR;
            const int r = base + row;
            float4 v = make_float4(0.f, 0.f, 0.f, 0.f);
            if (r < nout) {
                const int idx = nmap[(size_t)r * K + k];
                if (idx < nin) {
                    v = reinterpret_cast<const float4*>(fin + (size_t)idx * CIN)[q];
                    if (AFF) {
                        const float4 a = reinterpret_cast<const float4*>(affA)[q];
                        const float4 b = reinterpret_cast<const float4*>(affB)[q];
                        v.x = fmaf(v.x, a.x, b.x);
                        v.y = fmaf(v.y, a.y, b.y);
                        v.z = fmaf(v.z, a.z, b.z);
                        v.w = fmaf(v.w, a.w, b.w);
                    }
                }
            }
            *reinterpret_cast<float4*>(&lds[row * STRIDE + q * 4]) = v;
        }
        __syncthreads();

        // ---- compute: acc[i][j] += g[row_i][ci] * W[k][ci][col_j] ----
        const float* __restrict__ Wk = W + (size_t)k * CIN * 64;
#pragma unroll 4
        for (int c4 = 0; c4 < QPR; ++c4) {
            const float4 w0 = *reinterpret_cast<const float4*>(Wk + (c4 * 4 + 0) * 64 + tx * 4);
            const float4 w1 = *reinterpret_cast<const float4*>(Wk + (c4 * 4 + 1) * 64 + tx * 4);
            const float4 w2 = *reinterpret_cast<const float4*>(Wk + (c4 * 4 + 2) * 64 + tx * 4);
            const float4 w3 = *reinterpret_cast<const float4*>(Wk + (c4 * 4 + 3) * 64 + tx * 4);
            float4 g[4];
#pragma unroll
            for (int i = 0; i < 4; ++i)
                g[i] = *reinterpret_cast<const float4*>(&lds[(ty * 4 + i) * STRIDE + c4 * 4]);
#pragma unroll
            for (int i = 0; i < 4; ++i) {
                const float4 gi = g[i];
                acc[i][0] = fmaf(gi.x, w0.x, fmaf(gi.y, w1.x, fmaf(gi.z, w2.x, fmaf(gi.w, w3.x, acc[i][0]))));
                acc[i][1] = fmaf(gi.x, w0.y, fmaf(gi.y, w1.y, fmaf(gi.z, w2.y, fmaf(gi.w, w3.y, acc[i][1]))));
                acc[i][2] = fmaf(gi.x, w0.z, fmaf(gi.y, w1.z, fmaf(gi.z, w2.z, fmaf(gi.w, w3.z, acc[i][2]))));
                acc[i][3] = fmaf(gi.x, w0.w, fmaf(gi.y, w1.w, fmaf(gi.z, w2.w, fmaf(gi.w, w3.w, acc[i][3]))));
            }
        }
    }

    // ---- epilogue: bias (+ leaky relu), store ----
    const float4 bv = *reinterpret_cast<const float4*>(bias + tx * 4);
#pragma unroll
    for (int i = 0; i < 4; ++i) {
        const int r = base + ty * 4 + i;
        if (r < nout) {
            float4 o;
            o.x = acc[i][0] + bv.x;
            o.y = acc[i][1] + bv.y;
            o.z = acc[i][2] + bv.z;
            o.w = acc[i][3] + bv.w;
            if (LEAKY) {
                o.x = o.x >= 0.f ? o.x : LRELU_SLOPE * o.x;
                o.y = o.y >= 0.f ? o.y : LRELU_SLOPE * o.y;
                o.z = o.z >= 0.f ? o.z : LRELU_SLOPE * o.z;
                o.w = o.w >= 0.f ? o.w : LRELU_SLOPE * o.w;
            }
            *reinterpret_cast<float4*>(fout + (size_t)r * 64 + tx * 4) = o;
        }
    }
}

// ---------------------------------------------------------------------------
// BatchNorm stage 1: deterministic per-block partial sum/sumsq per channel.
// partials[b][c] = sum, partials[b][64+c] = sumsq  over this block's rows.
// ---------------------------------------------------------------------------
__global__ __launch_bounds__(256) void bn_partial(const float* __restrict__ f2, int n2,
                                                  float* __restrict__ partials)
{
    const int c = threadIdx.x & 63;
    const int g = threadIdx.x >> 6;  // 0..3
    float s = 0.f, ss = 0.f;
    for (int r = blockIdx.x * 4 + g; r < n2; r += gridDim.x * 4) {
        const float v = f2[(size_t)r * 64 + c];
        s += v;
        ss = fmaf(v, v, ss);
    }
    __shared__ float red[4][128];
    red[g][c] = s;
    red[g][64 + c] = ss;
    __syncthreads();
    if (g == 0) {
        const float S = red[0][c] + red[1][c] + red[2][c] + red[3][c];
        const float SS = red[0][64 + c] + red[1][64 + c] + red[2][64 + c] + red[3][64 + c];
        partials[(size_t)blockIdx.x * 128 + c] = S;
        partials[(size_t)blockIdx.x * 128 + 64 + c] = SS;
    }
}

// ---------------------------------------------------------------------------
// BatchNorm stage 2: final reduce -> per-channel affine a,b with scale folded:
//   f3 = (f2 - mu) * rsqrt(var+eps) * gamma + beta, then * scale
//      = f2 * a + b,  a = rs*gamma*scale,  b = (beta - mu*rs*gamma)*scale
// ---------------------------------------------------------------------------
__global__ __launch_bounds__(64) void bn_finalize(const float* __restrict__ partials, int nb, int n2,
                                                  const float* __restrict__ gamma,
                                                  const float* __restrict__ beta,
                                                  const float* __restrict__ scale,
                                                  float* __restrict__ affA, float* __restrict__ affB)
{
    const int c = threadIdx.x;  // 0..63
    float S = 0.f, SS = 0.f;
    for (int b = 0; b < nb; ++b) {
        S += partials[(size_t)b * 128 + c];
        SS += partials[(size_t)b * 128 + 64 + c];
    }
    const float inv_n = 1.f / (float)n2;
    const float mu = S * inv_n;
    const float var = fmaxf(SS * inv_n - mu * mu, 0.f);
    const float rs = rsqrtf(var + 1e-5f);
    const float sc = scale[0];
    const float ga = gamma[c];
    affA[c] = rs * ga * sc;
    affB[c] = (beta[c] - mu * rs * ga) * sc;
}

extern "C" void kernel_launch(void* const* d_in, const int* in_sizes, int n_in,
                              void* d_out, int out_size, void* d_ws, size_t ws_size,
                              hipStream_t stream)
{
    const float* x     = (const float*)d_in[0];
    const float* W1    = (const float*)d_in[1];
    const float* b1    = (const float*)d_in[2];
    const float* W2    = (const float*)d_in[3];
    const float* b2    = (const float*)d_in[4];
    const float* W3    = (const float*)d_in[5];
    const float* b3    = (const float*)d_in[6];
    const float* gamma = (const float*)d_in[7];
    const float* beta  = (const float*)d_in[8];
    const float* scale = (const float*)d_in[9];
    const int* nmap1   = (const int*)d_in[10];
    const int* nmap2   = (const int*)d_in[11];
    const int* nmap3   = (const int*)d_in[12];

    const int N  = in_sizes[0] / 96;    // stride-1 points
    const int N2 = in_sizes[11] / 8;    // stride-2 points

    float* f1       = (float*)d_ws;                  // [N ,64]
    float* f2       = f1 + (size_t)N * 64;           // [N2,64]
    float* partials = f2 + (size_t)N2 * 64;          // [BN_NB,128]
    float* affA     = partials + (size_t)BN_NB * 128;// [64]
    float* affB     = affA + 64;                     // [64]
    float* out      = (float*)d_out;                 // [N2,64]

    // conv1: k=27, 96->64, leaky
    sconv_kernel<27, 96, true, false><<<(N + 63) / 64, 256, 0, stream>>>(
        x, N, nmap1, W1, b1, nullptr, nullptr, f1, N);
    // conv2: k=8, 64->64, leaky (downsample)
    sconv_kernel<8, 64, true, false><<<(N2 + 63) / 64, 256, 0, stream>>>(
        f1, N, nmap2, W2, b2, nullptr, nullptr, f2, N2);
    // batchnorm stats (deterministic two-stage)
    bn_partial<<<BN_NB, 256, 0, stream>>>(f2, N2, partials);
    bn_finalize<<<1, 64, 0, stream>>>(partials, BN_NB, N2, gamma, beta, scale, affA, affB);
    // conv3: k=27, 64->64, BN affine fused into gather, no activation
    sconv_kernel<27, 64, false, true><<<(N2 + 63) / 64, 256, 0, stream>>>(
        f2, N2, nmap3, W3, b3, affA, affB, out, N2);
}

// Round 2
// 231.820 us; speedup vs baseline: 3.1768x; 3.1768x over previous
//
#include <hip/hip_runtime.h>
#include <cstdint>

typedef __attribute__((ext_vector_type(8))) short bf16x8;
typedef __attribute__((ext_vector_type(4))) float f32x4;

#define BN_NB 256
#define LRELU_SLOPE 0.1f

__device__ __forceinline__ float bf2f(ushort h) {
    union { uint u; float v; } x; x.u = ((uint)h) << 16; return x.v;
}
__device__ __forceinline__ ushort f2bf(float f) {
    union { float v; uint u; } x; x.v = f;
    const uint r = (x.u + 0x7FFFu + ((x.u >> 16) & 1u)) >> 16;  // RNE
    return (ushort)r;
}

// ---------------------------------------------------------------------------
// x (fp32) -> bf16, vectorized
// ---------------------------------------------------------------------------
__global__ __launch_bounds__(256) void cvt_bf16(const float* __restrict__ in,
                                                ushort* __restrict__ out, int n4)
{
    for (int i = blockIdx.x * 256 + threadIdx.x; i < n4; i += gridDim.x * 256) {
        const float4 v = reinterpret_cast<const float4*>(in)[i];
        ushort4 o;
        o.x = f2bf(v.x); o.y = f2bf(v.y); o.z = f2bf(v.z); o.w = f2bf(v.w);
        reinterpret_cast<ushort4*>(out)[i] = o;
    }
}

// ---------------------------------------------------------------------------
// Pack W[K][CIN][64] fp32 -> bf16 B-fragments.
// Slice s = (tap*KB + kb)*4 + cb; lane l holds W[kb*32+(l>>4)*8+e][cb*16+(l&15)].
// ---------------------------------------------------------------------------
template<int K, int CIN>
__global__ __launch_bounds__(256) void pack_W(const float* __restrict__ W,
                                              ushort* __restrict__ Bp)
{
    constexpr int KB = CIN / 32;
    const int t = blockIdx.x * 256 + threadIdx.x;
    if (t >= K * KB * 4 * 64) return;
    const int l = t & 63;
    const int s = t >> 6;
    const int cb = s & 3;
    const int kk = s >> 2;
    const int kb = kk % KB;
    const int tap = kk / KB;
    const int k0 = kb * 32 + (l >> 4) * 8;
    const int col = cb * 16 + (l & 15);
    bf16x8 v;
#pragma unroll
    for (int e = 0; e < 8; ++e)
        v[e] = (short)f2bf(W[((size_t)tap * CIN + k0 + e) * 64 + col]);
    *reinterpret_cast<bf16x8*>(Bp + (size_t)t * 8) = v;
}

// ---------------------------------------------------------------------------
// Gather-GEMM sparse conv via MFMA 16x16x32 bf16.
// Block: 256 thr = 4 waves, 64 output rows. Wave w: rows w*16..w*16+15 x 64 cols.
// Per tap: gather 64 rows (bf16) into LDS (stride CIN+8 ushorts -> 2-way bank
// aliasing on the fragment ds_read_b128, free), then KB x 4 MFMAs per wave.
// AFF: per-input-channel affine (BatchNorm+scale) applied during gather.
// ---------------------------------------------------------------------------
template<int K, int CIN, bool LEAKY, bool AFF, bool OUTF32>
__global__ __launch_bounds__(256) void sconv_mfma(
    const ushort* __restrict__ fin, int nin,
    const int* __restrict__ nmap,
    const ushort* __restrict__ Bp,
    const float* __restrict__ bias,
    const float* __restrict__ affA,
    const float* __restrict__ affB,
    void* __restrict__ fout, int nout)
{
    constexpr int KB = CIN / 32;   // MFMA K-blocks per tap
    constexpr int CPR = CIN / 8;   // 16B chunks per feature row
    constexpr int LRW = CIN + 8;   // LDS row stride in ushorts (+16B pad)
    __shared__ ushort Alds[64 * LRW];
    __shared__ int idxc[64 * K];

    const int tid = threadIdx.x;
    const int l = tid & 63;
    const int w = tid >> 6;
    const int base = blockIdx.x * 64;

    // cache this block's nmap rows (coalesced)
    for (int e = tid; e < 64 * K; e += 256) {
        const int r = base + e / K;
        idxc[e] = (r < nout) ? nmap[(size_t)r * K + (e - (e / K) * K)] : nin;
    }

    f32x4 acc[4];
#pragma unroll
    for (int cb = 0; cb < 4; ++cb) acc[cb] = (f32x4){0.f, 0.f, 0.f, 0.f};

    __syncthreads();

    for (int k = 0; k < K; ++k) {
        // ---- stage gathered tap-k rows into LDS ----
#pragma unroll
        for (int e = tid; e < 64 * CPR; e += 256) {
            const int row = e / CPR;
            const int c = e - row * CPR;
            const int idx = idxc[row * K + k];
            bf16x8 v = {0, 0, 0, 0, 0, 0, 0, 0};
            if (idx < nin) {
                v = *reinterpret_cast<const bf16x8*>(fin + (size_t)idx * CIN + c * 8);
                if (AFF) {
#pragma unroll
                    for (int j = 0; j < 8; ++j) {
                        const float av = affA[c * 8 + j];
                        const float bv = affB[c * 8 + j];
                        v[j] = (short)f2bf(fmaf(bf2f((ushort)v[j]), av, bv));
                    }
                }
            }
            *reinterpret_cast<bf16x8*>(&Alds[row * LRW + c * 8]) = v;
        }
        __syncthreads();

        // ---- MFMA: A-frag lane l -> row (l&15), k = (l>>4)*8..+7 ----
        const int arow = w * 16 + (l & 15);
#pragma unroll
        for (int kb = 0; kb < KB; ++kb) {
            const int c = kb * 4 + (l >> 4);
            const bf16x8 a = *reinterpret_cast<const bf16x8*>(&Alds[arow * LRW + c * 8]);
            const bf16x8* bp = reinterpret_cast<const bf16x8*>(Bp)
                             + ((size_t)(k * KB + kb) * 4) * 64 + l;
            acc[0] = __builtin_amdgcn_mfma_f32_16x16x32_bf16(a, bp[0],   acc[0], 0, 0, 0);
            acc[1] = __builtin_amdgcn_mfma_f32_16x16x32_bf16(a, bp[64],  acc[1], 0, 0, 0);
            acc[2] = __builtin_amdgcn_mfma_f32_16x16x32_bf16(a, bp[128], acc[2], 0, 0, 0);
            acc[3] = __builtin_amdgcn_mfma_f32_16x16x32_bf16(a, bp[192], acc[3], 0, 0, 0);
        }
        __syncthreads();
    }

    // ---- epilogue: D row = (l>>4)*4+reg, col = l&15 (m89-verified) ----
    const int r0 = base + w * 16 + (l >> 4) * 4;
#pragma unroll
    for (int cb = 0; cb < 4; ++cb) {
        const int col = cb * 16 + (l & 15);
        const float bcol = bias[col];
#pragma unroll
        for (int i = 0; i < 4; ++i) {
            const int r = r0 + i;
            if (r < nout) {
                float o = acc[cb][i] + bcol;
                if (LEAKY) o = o >= 0.f ? o : LRELU_SLOPE * o;
                if (OUTF32) reinterpret_cast<float*>(fout)[(size_t)r * 64 + col] = o;
                else        reinterpret_cast<ushort*>(fout)[(size_t)r * 64 + col] = f2bf(o);
            }
        }
    }
}

// ---------------------------------------------------------------------------
// BatchNorm stage 1 (bf16 input): deterministic per-block partial sum/sumsq.
// ---------------------------------------------------------------------------
__global__ __launch_bounds__(256) void bn_partial(const ushort* __restrict__ f2v, int n2,
                                                  float* __restrict__ partials)
{
    const int c = threadIdx.x & 63;
    const int g = threadIdx.x >> 6;
    float s = 0.f, ss = 0.f;
    for (int r = blockIdx.x * 4 + g; r < n2; r += gridDim.x * 4) {
        const float v = bf2f(f2v[(size_t)r * 64 + c]);
        s += v;
        ss = fmaf(v, v, ss);
    }
    __shared__ float red[4][128];
    red[g][c] = s;
    red[g][64 + c] = ss;
    __syncthreads();
    if (g == 0) {
        partials[(size_t)blockIdx.x * 128 + c] =
            red[0][c] + red[1][c] + red[2][c] + red[3][c];
        partials[(size_t)blockIdx.x * 128 + 64 + c] =
            red[0][64 + c] + red[1][64 + c] + red[2][64 + c] + red[3][64 + c];
    }
}

// ---------------------------------------------------------------------------
// BatchNorm stage 2: f3 = f2*a + b with scale folded.
// ---------------------------------------------------------------------------
__global__ __launch_bounds__(64) void bn_finalize(const float* __restrict__ partials, int nb, int n2,
                                                  const float* __restrict__ gamma,
                                                  const float* __restrict__ beta,
                                                  const float* __restrict__ scale,
                                                  float* __restrict__ affA, float* __restrict__ affB)
{
    const int c = threadIdx.x;  // 0..63
    float S = 0.f, SS = 0.f;
    for (int b = 0; b < nb; ++b) {
        S += partials[(size_t)b * 128 + c];
        SS += partials[(size_t)b * 128 + 64 + c];
    }
    const float inv_n = 1.f / (float)n2;
    const float mu = S * inv_n;
    const float var = fmaxf(SS * inv_n - mu * mu, 0.f);
    const float rs = rsqrtf(var + 1e-5f);
    const float sc = scale[0];
    const float ga = gamma[c];
    affA[c] = rs * ga * sc;
    affB[c] = (beta[c] - mu * rs * ga) * sc;
}

extern "C" void kernel_launch(void* const* d_in, const int* in_sizes, int n_in,
                              void* d_out, int out_size, void* d_ws, size_t ws_size,
                              hipStream_t stream)
{
    const float* x     = (const float*)d_in[0];
    const float* W1    = (const float*)d_in[1];
    const float* b1    = (const float*)d_in[2];
    const float* W2    = (const float*)d_in[3];
    const float* b2    = (const float*)d_in[4];
    const float* W3    = (const float*)d_in[5];
    const float* b3    = (const float*)d_in[6];
    const float* gamma = (const float*)d_in[7];
    const float* beta  = (const float*)d_in[8];
    const float* scale = (const float*)d_in[9];
    const int* nmap1   = (const int*)d_in[10];
    const int* nmap2   = (const int*)d_in[11];
    const int* nmap3   = (const int*)d_in[12];

    const int N  = in_sizes[0] / 96;    // stride-1 points
    const int N2 = in_sizes[11] / 8;    // stride-2 points

    // workspace (all bf16 regions 16B-aligned)
    ushort* xb  = (ushort*)d_ws;                    // [N ,96] bf16
    ushort* f1  = xb + (size_t)N * 96;              // [N ,64] bf16
    ushort* f2  = f1 + (size_t)N * 64;              // [N2,64] bf16
    ushort* Bp1 = f2 + (size_t)N2 * 64;             // 27*96*64 bf16
    ushort* Bp2 = Bp1 + 27 * 96 * 64;               // 8*64*64
    ushort* Bp3 = Bp2 + 8 * 64 * 64;                // 27*64*64
    float* partials = (float*)(Bp3 + 27 * 64 * 64); // [BN_NB,128]
    float* affA = partials + (size_t)BN_NB * 128;   // [64]
    float* affB = affA + 64;                        // [64]
    float* out  = (float*)d_out;                    // [N2,64] fp32

    // x -> bf16
    const int n4 = N * 96 / 4;
    cvt_bf16<<<2048, 256, 0, stream>>>(x, xb, n4);
    // weight packing (one-shot, tiny)
    pack_W<27, 96><<<(27 * 3 * 4 * 64 + 255) / 256, 256, 0, stream>>>(W1, Bp1);
    pack_W<8, 64><<<(8 * 2 * 4 * 64 + 255) / 256, 256, 0, stream>>>(W2, Bp2);
    pack_W<27, 64><<<(27 * 2 * 4 * 64 + 255) / 256, 256, 0, stream>>>(W3, Bp3);

    // conv1: k=27, 96->64, leaky
    sconv_mfma<27, 96, true, false, false><<<(N + 63) / 64, 256, 0, stream>>>(
        xb, N, nmap1, Bp1, b1, nullptr, nullptr, f1, N);
    // conv2: k=8, 64->64, leaky (downsample)
    sconv_mfma<8, 64, true, false, false><<<(N2 + 63) / 64, 256, 0, stream>>>(
        f1, N, nmap2, Bp2, b2, nullptr, nullptr, f2, N2);
    // batchnorm stats (deterministic two-stage)
    bn_partial<<<BN_NB, 256, 0, stream>>>(f2, N2, partials);
    bn_finalize<<<1, 64, 0, stream>>>(partials, BN_NB, N2, gamma, beta, scale, affA, affB);
    // conv3: k=27, 64->64, BN affine fused into gather, fp32 out
    sconv_mfma<27, 64, false, true, true><<<(N2 + 63) / 64, 256, 0, stream>>>(
        f2, N2, nmap3, Bp3, b3, affA, affB, out, N2);
}

// Round 3
// 209.785 us; speedup vs baseline: 3.5105x; 1.1050x over previous
//
#include <hip/hip_runtime.h>
#include <cstdint>

typedef __attribute__((ext_vector_type(8))) short bf16x8;
typedef __attribute__((ext_vector_type(4))) float f32x4;

#define BN_NB 256
#define LRELU_SLOPE 0.1f

__device__ __forceinline__ float bf2f(ushort h) {
    union { uint u; float v; } x; x.u = ((uint)h) << 16; return x.v;
}
__device__ __forceinline__ ushort f2bf(float f) {
    union { float v; uint u; } x; x.v = f;
    const uint r = (x.u + 0x7FFFu + ((x.u >> 16) & 1u)) >> 16;  // RNE
    return (ushort)r;
}

// ---------------------------------------------------------------------------
// x (fp32) -> bf16, vectorized
// ---------------------------------------------------------------------------
__global__ __launch_bounds__(256) void cvt_bf16(const float* __restrict__ in,
                                                ushort* __restrict__ out, int n4)
{
    for (int i = blockIdx.x * 256 + threadIdx.x; i < n4; i += gridDim.x * 256) {
        const float4 v = reinterpret_cast<const float4*>(in)[i];
        ushort4 o;
        o.x = f2bf(v.x); o.y = f2bf(v.y); o.z = f2bf(v.z); o.w = f2bf(v.w);
        reinterpret_cast<ushort4*>(out)[i] = o;
    }
}

// ---------------------------------------------------------------------------
// Zero the sentinel rows appended to each feature table.
// ---------------------------------------------------------------------------
__global__ __launch_bounds__(128) void zero_rows(ushort* __restrict__ xbz,
                                                 ushort* __restrict__ f1z,
                                                 ushort* __restrict__ f2z)
{
    const int t = threadIdx.x;
    if (t < 96) xbz[t] = 0;
    if (t < 64) { f1z[t] = 0; f2z[t] = 0; }
}

// ---------------------------------------------------------------------------
// Pack W[K][CIN][64] fp32 -> bf16 B-fragments.
// Slice s = (tap*KB + kb)*4 + cb; lane l holds W[kb*32+(l>>4)*8+e][cb*16+(l&15)].
// ---------------------------------------------------------------------------
template<int K, int CIN>
__global__ __launch_bounds__(256) void pack_W(const float* __restrict__ W,
                                              ushort* __restrict__ Bp)
{
    constexpr int KB = CIN / 32;
    const int t = blockIdx.x * 256 + threadIdx.x;
    if (t >= K * KB * 4 * 64) return;
    const int l = t & 63;
    const int s = t >> 6;
    const int cb = s & 3;
    const int kk = s >> 2;
    const int kb = kk % KB;
    const int tap = kk / KB;
    const int k0 = kb * 32 + (l >> 4) * 8;
    const int col = cb * 16 + (l & 15);
    bf16x8 v;
#pragma unroll
    for (int e = 0; e < 8; ++e)
        v[e] = (short)f2bf(W[((size_t)tap * CIN + k0 + e) * 64 + col]);
    *reinterpret_cast<bf16x8*>(Bp + (size_t)t * 8) = v;
}

// ---------------------------------------------------------------------------
// Direct-gather sparse conv via MFMA 16x16x32 bf16. NO LDS staging of A:
// lane l gathers its A-fragment (16B) straight from global (L2-resident),
// software-prefetching the next tap's fragments during the current MFMAs.
// No barriers in the main loop -> waves drift and hide each other's latency.
// Sentinel nmap entries point at an appended all-zero feature row.
// Block: 256 thr = 4 waves, 64 output rows; wave w: rows w*16..+15 x 64 cols.
// ---------------------------------------------------------------------------
template<int K, int CIN, bool LEAKY, bool OUTF32>
__global__ __launch_bounds__(256) void sconv_dg(
    const ushort* __restrict__ fin,      // [nin+1][CIN], row nin == zeros
    const int* __restrict__ nmap,        // [nout][K]
    const ushort* __restrict__ Bp,       // packed B fragments
    const float* __restrict__ bias,      // [64]
    void* __restrict__ fout, int nout)
{
    constexpr int KB = CIN / 32;
    __shared__ int idxc[64 * K];

    const int tid = threadIdx.x;
    const int l = tid & 63;
    const int w = tid >> 6;
    const int base = blockIdx.x * 64;

    // cache this block's nmap rows (coalesced); OOB rows use row 0 (discarded)
    for (int e = tid; e < 64 * K; e += 256) {
        const int r = base + e / K;
        idxc[e] = (r < nout) ? nmap[(size_t)r * K + (e % K)] : 0;
    }
    __syncthreads();

    const int lrow = l & 15;
    const int grp = l >> 4;
    const int myrow = w * 16 + lrow;
    const int koff = grp * 8;                 // ushort offset inside a 32-k chunk

    f32x4 acc[4];
#pragma unroll
    for (int cb = 0; cb < 4; ++cb) acc[cb] = (f32x4){0.f, 0.f, 0.f, 0.f};

    const bf16x8* __restrict__ B8 = reinterpret_cast<const bf16x8*>(Bp);

    bf16x8 a_cur[KB];
    {
        const size_t idx = (size_t)idxc[myrow * K];
#pragma unroll
        for (int kb = 0; kb < KB; ++kb)
            a_cur[kb] = *reinterpret_cast<const bf16x8*>(fin + idx * CIN + kb * 32 + koff);
    }

    for (int k = 0; k < K; ++k) {
        // prefetch next tap's A-fragments (clamped on last iter; uniform branch-free)
        const int kn = (k + 1 < K) ? k + 1 : k;
        const size_t idxn = (size_t)idxc[myrow * K + kn];
        bf16x8 a_nxt[KB];
#pragma unroll
        for (int kb = 0; kb < KB; ++kb)
            a_nxt[kb] = *reinterpret_cast<const bf16x8*>(fin + idxn * CIN + kb * 32 + koff);

        const bf16x8* __restrict__ bk = B8 + (size_t)k * KB * 4 * 64 + l;
#pragma unroll
        for (int kb = 0; kb < KB; ++kb) {
#pragma unroll
            for (int cb = 0; cb < 4; ++cb)
                acc[cb] = __builtin_amdgcn_mfma_f32_16x16x32_bf16(
                    a_cur[kb], bk[(kb * 4 + cb) * 64], acc[cb], 0, 0, 0);
        }
#pragma unroll
        for (int kb = 0; kb < KB; ++kb) a_cur[kb] = a_nxt[kb];
    }

    // ---- epilogue: D row = (l>>4)*4+i, col = l&15 ----
    const int r0 = base + w * 16 + grp * 4;
#pragma unroll
    for (int cb = 0; cb < 4; ++cb) {
        const int col = cb * 16 + lrow;
        const float bcol = bias[col];
#pragma unroll
        for (int i = 0; i < 4; ++i) {
            const int r = r0 + i;
            if (r < nout) {
                float o = acc[cb][i] + bcol;
                if (LEAKY) o = o >= 0.f ? o : LRELU_SLOPE * o;
                if (OUTF32) reinterpret_cast<float*>(fout)[(size_t)r * 64 + col] = o;
                else        reinterpret_cast<ushort*>(fout)[(size_t)r * 64 + col] = f2bf(o);
            }
        }
    }
}

// ---------------------------------------------------------------------------
// BatchNorm stage 1 (bf16 input): deterministic per-block partial sum/sumsq.
// ---------------------------------------------------------------------------
__global__ __launch_bounds__(256) void bn_partial(const ushort* __restrict__ f2v, int n2,
                                                  float* __restrict__ partials)
{
    const int c = threadIdx.x & 63;
    const int g = threadIdx.x >> 6;
    float s = 0.f, ss = 0.f;
    for (int r = blockIdx.x * 4 + g; r < n2; r += gridDim.x * 4) {
        const float v = bf2f(f2v[(size_t)r * 64 + c]);
        s += v;
        ss = fmaf(v, v, ss);
    }
    __shared__ float red[4][128];
    red[g][c] = s;
    red[g][64 + c] = ss;
    __syncthreads();
    if (g == 0) {
        partials[(size_t)blockIdx.x * 128 + c] =
            red[0][c] + red[1][c] + red[2][c] + red[3][c];
        partials[(size_t)blockIdx.x * 128 + 64 + c] =
            red[0][64 + c] + red[1][64 + c] + red[2][64 + c] + red[3][64 + c];
    }
}

// ---------------------------------------------------------------------------
// BatchNorm stage 2: per-channel affine a,b with scale folded.
// ---------------------------------------------------------------------------
__global__ __launch_bounds__(64) void bn_finalize(const float* __restrict__ partials, int nb, int n2,
                                                  const float* __restrict__ gamma,
                                                  const float* __restrict__ beta,
                                                  const float* __restrict__ scale,
                                                  float* __restrict__ affA, float* __restrict__ affB)
{
    const int c = threadIdx.x;  // 0..63
    float S = 0.f, SS = 0.f;
    for (int b = 0; b < nb; ++b) {
        S += partials[(size_t)b * 128 + c];
        SS += partials[(size_t)b * 128 + 64 + c];
    }
    const float inv_n = 1.f / (float)n2;
    const float mu = S * inv_n;
    const float var = fmaxf(SS * inv_n - mu * mu, 0.f);
    const float rs = rsqrtf(var + 1e-5f);
    const float sc = scale[0];
    const float ga = gamma[c];
    affA[c] = rs * ga * sc;
    affB[c] = (beta[c] - mu * rs * ga) * sc;
}

// ---------------------------------------------------------------------------
// In-place BN affine on f2 (bf16): f2 = f2*a + b. Elementwise, deterministic.
// ---------------------------------------------------------------------------
__global__ __launch_bounds__(256) void aff_apply(ushort* __restrict__ f2, int nchunk,
                                                 const float* __restrict__ affA,
                                                 const float* __restrict__ affB)
{
    for (int i = blockIdx.x * 256 + threadIdx.x; i < nchunk; i += gridDim.x * 256) {
        const int c = i & 7;  // chunk-within-row
        bf16x8 v = *reinterpret_cast<const bf16x8*>(f2 + (size_t)i * 8);
#pragma unroll
        for (int j = 0; j < 8; ++j)
            v[j] = (short)f2bf(fmaf(bf2f((ushort)v[j]), affA[c * 8 + j], affB[c * 8 + j]));
        *reinterpret_cast<bf16x8*>(f2 + (size_t)i * 8) = v;
    }
}

extern "C" void kernel_launch(void* const* d_in, const int* in_sizes, int n_in,
                              void* d_out, int out_size, void* d_ws, size_t ws_size,
                              hipStream_t stream)
{
    const float* x     = (const float*)d_in[0];
    const float* W1    = (const float*)d_in[1];
    const float* b1    = (const float*)d_in[2];
    const float* W2    = (const float*)d_in[3];
    const float* b2    = (const float*)d_in[4];
    const float* W3    = (const float*)d_in[5];
    const float* b3    = (const float*)d_in[6];
    const float* gamma = (const float*)d_in[7];
    const float* beta  = (const float*)d_in[8];
    const float* scale = (const float*)d_in[9];
    const int* nmap1   = (const int*)d_in[10];
    const int* nmap2   = (const int*)d_in[11];
    const int* nmap3   = (const int*)d_in[12];

    const int N  = in_sizes[0] / 96;    // stride-1 points
    const int N2 = in_sizes[11] / 8;    // stride-2 points

    // workspace (all regions 16B-aligned; +1 zero row per feature table)
    ushort* xb  = (ushort*)d_ws;                    // [N+1,96] bf16
    ushort* f1  = xb + (size_t)(N + 1) * 96;        // [N+1,64] bf16
    ushort* f2  = f1 + (size_t)(N + 1) * 64;        // [N2+1,64] bf16
    ushort* Bp1 = f2 + (size_t)(N2 + 1) * 64;       // 27*96*64 bf16
    ushort* Bp2 = Bp1 + 27 * 96 * 64;               // 8*64*64
    ushort* Bp3 = Bp2 + 8 * 64 * 64;                // 27*64*64
    float* partials = (float*)(Bp3 + 27 * 64 * 64); // [BN_NB,128]
    float* affA = partials + (size_t)BN_NB * 128;   // [64]
    float* affB = affA + 64;                        // [64]
    float* out  = (float*)d_out;                    // [N2,64] fp32

    // sentinel zero rows + input conversion + weight packing
    zero_rows<<<1, 128, 0, stream>>>(xb + (size_t)N * 96, f1 + (size_t)N * 64,
                                     f2 + (size_t)N2 * 64);
    cvt_bf16<<<2048, 256, 0, stream>>>(x, xb, N * 96 / 4);
    pack_W<27, 96><<<(27 * 3 * 4 * 64 + 255) / 256, 256, 0, stream>>>(W1, Bp1);
    pack_W<8, 64><<<(8 * 2 * 4 * 64 + 255) / 256, 256, 0, stream>>>(W2, Bp2);
    pack_W<27, 64><<<(27 * 2 * 4 * 64 + 255) / 256, 256, 0, stream>>>(W3, Bp3);

    // conv1: k=27, 96->64, leaky
    sconv_dg<27, 96, true, false><<<(N + 63) / 64, 256, 0, stream>>>(
        xb, nmap1, Bp1, b1, f1, N);
    // conv2: k=8, 64->64, leaky (downsample)
    sconv_dg<8, 64, true, false><<<(N2 + 63) / 64, 256, 0, stream>>>(
        f1, nmap2, Bp2, b2, f2, N2);
    // batchnorm stats + in-place affine (scale folded)
    bn_partial<<<BN_NB, 256, 0, stream>>>(f2, N2, partials);
    bn_finalize<<<1, 64, 0, stream>>>(partials, BN_NB, N2, gamma, beta, scale, affA, affB);
    aff_apply<<<2048, 256, 0, stream>>>(f2, N2 * 8, affA, affB);
    // conv3: k=27, 64->64, fp32 out
    sconv_dg<27, 64, false, true><<<(N2 + 63) / 64, 256, 0, stream>>>(
        f2, nmap3, Bp3, b3, out, N2);
}

// Round 4
// 158.613 us; speedup vs baseline: 4.6431x; 1.3226x over previous
//
#include <hip/hip_runtime.h>
#include <cstdint>

typedef __attribute__((ext_vector_type(8))) short bf16x8;
typedef __attribute__((ext_vector_type(4))) float f32x4;

#define BN_NB 256
#define LRELU_SLOPE 0.1f

__device__ __forceinline__ float bf2f(ushort h) {
    union { uint u; float v; } x; x.u = ((uint)h) << 16; return x.v;
}
__device__ __forceinline__ ushort f2bf(float f) {
    union { float v; uint u; } x; x.v = f;
    const uint r = (x.u + 0x7FFFu + ((x.u >> 16) & 1u)) >> 16;  // RNE
    return (ushort)r;
}

// m204 bijective XCD swizzle: contiguous grid chunk per XCD (8 XCDs).
__device__ __forceinline__ int xcd_swizzle(int bid, int nwg) {
    const int q = nwg >> 3, r = nwg & 7;
    const int xcd = bid & 7, local = bid >> 3;
    return (xcd < r ? xcd * (q + 1) : r * (q + 1) + (xcd - r) * q) + local;
}

// ---------------------------------------------------------------------------
// x (fp32) -> bf16, vectorized
// ---------------------------------------------------------------------------
__global__ __launch_bounds__(256) void cvt_bf16(const float* __restrict__ in,
                                                ushort* __restrict__ out, int n4)
{
    for (int i = blockIdx.x * 256 + threadIdx.x; i < n4; i += gridDim.x * 256) {
        const float4 v = reinterpret_cast<const float4*>(in)[i];
        ushort4 o;
        o.x = f2bf(v.x); o.y = f2bf(v.y); o.z = f2bf(v.z); o.w = f2bf(v.w);
        reinterpret_cast<ushort4*>(out)[i] = o;
    }
}

// ---------------------------------------------------------------------------
// Zero the sentinel rows appended to each feature table.
// ---------------------------------------------------------------------------
__global__ __launch_bounds__(128) void zero_rows(ushort* __restrict__ xbz,
                                                 ushort* __restrict__ f1z,
                                                 ushort* __restrict__ f2z)
{
    const int t = threadIdx.x;
    if (t < 96) xbz[t] = 0;
    if (t < 64) { f1z[t] = 0; f2z[t] = 0; }
}

// ---------------------------------------------------------------------------
// Pack W[K][CIN][64] fp32 -> bf16 B-fragments.
// Slice s = (tap*KB + kb)*4 + cb; lane l holds W[kb*32+(l>>4)*8+e][cb*16+(l&15)].
// ---------------------------------------------------------------------------
template<int K, int CIN>
__global__ __launch_bounds__(256) void pack_W(const float* __restrict__ W,
                                              ushort* __restrict__ Bp)
{
    constexpr int KB = CIN / 32;
    const int t = blockIdx.x * 256 + threadIdx.x;
    if (t >= K * KB * 4 * 64) return;
    const int l = t & 63;
    const int s = t >> 6;
    const int cb = s & 3;
    const int kk = s >> 2;
    const int kb = kk % KB;
    const int tap = kk / KB;
    const int k0 = kb * 32 + (l >> 4) * 8;
    const int col = cb * 16 + (l & 15);
    bf16x8 v;
#pragma unroll
    for (int e = 0; e < 8; ++e)
        v[e] = (short)f2bf(W[((size_t)tap * CIN + k0 + e) * 64 + col]);
    *reinterpret_cast<bf16x8*>(Bp + (size_t)t * 8) = v;
}

// ---------------------------------------------------------------------------
// Direct-gather sparse conv via MFMA 16x16x32 bf16. No LDS staging of A:
// lane l gathers its 16B A-fragment straight from global (L2-resident),
// software-prefetching the next tap's fragments during the current MFMAs.
// No barriers in the main loop. Sentinel rows -> appended zero row.
// Block: 256 thr = 4 waves, 64 output rows; wave w: rows w*16..+15 x 64 cols.
// Grid is XCD-swizzled so neighboring gather rows stay in one XCD's L2.
// ---------------------------------------------------------------------------
template<int K, int CIN, bool LEAKY, bool OUTF32>
__global__ __launch_bounds__(256) void sconv_dg(
    const ushort* __restrict__ fin,      // [nin+1][CIN], row nin == zeros
    const int* __restrict__ nmap,        // [nout][K]
    const ushort* __restrict__ Bp,       // packed B fragments
    const float* __restrict__ bias,      // [64]
    void* __restrict__ fout, int nout)
{
    constexpr int KB = CIN / 32;
    __shared__ int idxc[64 * K];

    const int tid = threadIdx.x;
    const int l = tid & 63;
    const int w = tid >> 6;
    const int base = xcd_swizzle(blockIdx.x, gridDim.x) * 64;

    // cache this block's nmap rows (coalesced); OOB rows use row 0 (discarded)
    for (int e = tid; e < 64 * K; e += 256) {
        const int r = base + e / K;
        idxc[e] = (r < nout) ? nmap[(size_t)r * K + (e % K)] : 0;
    }
    __syncthreads();

    const int lrow = l & 15;
    const int grp = l >> 4;
    const int myrow = w * 16 + lrow;
    const int koff = grp * 8;                 // ushort offset inside a 32-k chunk

    f32x4 acc[4];
#pragma unroll
    for (int cb = 0; cb < 4; ++cb) acc[cb] = (f32x4){0.f, 0.f, 0.f, 0.f};

    const bf16x8* __restrict__ B8 = reinterpret_cast<const bf16x8*>(Bp);

    bf16x8 a_cur[KB];
    {
        const size_t idx = (size_t)idxc[myrow * K];
#pragma unroll
        for (int kb = 0; kb < KB; ++kb)
            a_cur[kb] = *reinterpret_cast<const bf16x8*>(fin + idx * CIN + kb * 32 + koff);
    }

    for (int k = 0; k < K; ++k) {
        // prefetch next tap's A-fragments (clamped on last iter)
        const int kn = (k + 1 < K) ? k + 1 : k;
        const size_t idxn = (size_t)idxc[myrow * K + kn];
        bf16x8 a_nxt[KB];
#pragma unroll
        for (int kb = 0; kb < KB; ++kb)
            a_nxt[kb] = *reinterpret_cast<const bf16x8*>(fin + idxn * CIN + kb * 32 + koff);

        const bf16x8* __restrict__ bk = B8 + (size_t)k * KB * 4 * 64 + l;
#pragma unroll
        for (int kb = 0; kb < KB; ++kb) {
#pragma unroll
            for (int cb = 0; cb < 4; ++cb)
                acc[cb] = __builtin_amdgcn_mfma_f32_16x16x32_bf16(
                    a_cur[kb], bk[(kb * 4 + cb) * 64], acc[cb], 0, 0, 0);
        }
#pragma unroll
        for (int kb = 0; kb < KB; ++kb) a_cur[kb] = a_nxt[kb];
    }

    // ---- epilogue: D row = (l>>4)*4+i, col = l&15 ----
    const int r0 = base + w * 16 + grp * 4;
#pragma unroll
    for (int cb = 0; cb < 4; ++cb) {
        const int col = cb * 16 + lrow;
        const float bcol = bias[col];
#pragma unroll
        for (int i = 0; i < 4; ++i) {
            const int r = r0 + i;
            if (r < nout) {
                float o = acc[cb][i] + bcol;
                if (LEAKY) o = o >= 0.f ? o : LRELU_SLOPE * o;
                if (OUTF32) reinterpret_cast<float*>(fout)[(size_t)r * 64 + col] = o;
                else        reinterpret_cast<ushort*>(fout)[(size_t)r * 64 + col] = f2bf(o);
            }
        }
    }
}

// ---------------------------------------------------------------------------
// BatchNorm stage 1 (bf16 input): deterministic per-block partial sum/sumsq.
// ---------------------------------------------------------------------------
__global__ __launch_bounds__(256) void bn_partial(const ushort* __restrict__ f2v, int n2,
                                                  float* __restrict__ partials)
{
    const int c = threadIdx.x & 63;
    const int g = threadIdx.x >> 6;
    float s = 0.f, ss = 0.f;
    for (int r = blockIdx.x * 4 + g; r < n2; r += gridDim.x * 4) {
        const float v = bf2f(f2v[(size_t)r * 64 + c]);
        s += v;
        ss = fmaf(v, v, ss);
    }
    __shared__ float red[4][128];
    red[g][c] = s;
    red[g][64 + c] = ss;
    __syncthreads();
    if (g == 0) {
        partials[(size_t)blockIdx.x * 128 + c] =
            red[0][c] + red[1][c] + red[2][c] + red[3][c];
        partials[(size_t)blockIdx.x * 128 + 64 + c] =
            red[0][64 + c] + red[1][64 + c] + red[2][64 + c] + red[3][64 + c];
    }
}

// ---------------------------------------------------------------------------
// BatchNorm stage 2: PARALLEL final reduce (1024 thr = 8 row-groups x 128 cols)
// -> per-channel affine a,b with scale folded:
//   f3 = f2 * a + b,  a = rs*gamma*scale,  b = (beta - mu*rs*gamma)*scale
// ---------------------------------------------------------------------------
__global__ __launch_bounds__(1024) void bn_finalize(const float* __restrict__ partials, int n2,
                                                    const float* __restrict__ gamma,
                                                    const float* __restrict__ beta,
                                                    const float* __restrict__ scale,
                                                    float* __restrict__ affA, float* __restrict__ affB)
{
    const int t = threadIdx.x;
    const int col = t & 127;   // 0..127 (sum | sumsq x 64 channels)
    const int g = t >> 7;      // 0..7
    float s = 0.f;
#pragma unroll
    for (int b = g; b < BN_NB; b += 8)
        s += partials[(size_t)b * 128 + col];
    __shared__ float red[8][128];
    red[g][col] = s;
    __syncthreads();
    if (g == 0) {
        float S = red[0][col];
#pragma unroll
        for (int i = 1; i < 8; ++i) S += red[i][col];
        red[0][col] = S;
    }
    __syncthreads();
    if (t < 64) {
        const float S = red[0][t];
        const float SS = red[0][64 + t];
        const float inv_n = 1.f / (float)n2;
        const float mu = S * inv_n;
        const float var = fmaxf(SS * inv_n - mu * mu, 0.f);
        const float rs = rsqrtf(var + 1e-5f);
        const float sc = scale[0];
        const float ga = gamma[t];
        affA[t] = rs * ga * sc;
        affB[t] = (beta[t] - mu * rs * ga) * sc;
    }
}

// ---------------------------------------------------------------------------
// In-place BN affine on f2 (bf16): f2 = f2*a + b. Elementwise, deterministic.
// ---------------------------------------------------------------------------
__global__ __launch_bounds__(256) void aff_apply(ushort* __restrict__ f2, int nchunk,
                                                 const float* __restrict__ affA,
                                                 const float* __restrict__ affB)
{
    for (int i = blockIdx.x * 256 + threadIdx.x; i < nchunk; i += gridDim.x * 256) {
        const int c = i & 7;  // chunk-within-row
        bf16x8 v = *reinterpret_cast<const bf16x8*>(f2 + (size_t)i * 8);
#pragma unroll
        for (int j = 0; j < 8; ++j)
            v[j] = (short)f2bf(fmaf(bf2f((ushort)v[j]), affA[c * 8 + j], affB[c * 8 + j]));
        *reinterpret_cast<bf16x8*>(f2 + (size_t)i * 8) = v;
    }
}

extern "C" void kernel_launch(void* const* d_in, const int* in_sizes, int n_in,
                              void* d_out, int out_size, void* d_ws, size_t ws_size,
                              hipStream_t stream)
{
    const float* x     = (const float*)d_in[0];
    const float* W1    = (const float*)d_in[1];
    const float* b1    = (const float*)d_in[2];
    const float* W2    = (const float*)d_in[3];
    const float* b2    = (const float*)d_in[4];
    const float* W3    = (const float*)d_in[5];
    const float* b3    = (const float*)d_in[6];
    const float* gamma = (const float*)d_in[7];
    const float* beta  = (const float*)d_in[8];
    const float* scale = (const float*)d_in[9];
    const int* nmap1   = (const int*)d_in[10];
    const int* nmap2   = (const int*)d_in[11];
    const int* nmap3   = (const int*)d_in[12];

    const int N  = in_sizes[0] / 96;    // stride-1 points
    const int N2 = in_sizes[11] / 8;    // stride-2 points

    // workspace (all regions 16B-aligned; +1 zero row per feature table)
    ushort* xb  = (ushort*)d_ws;                    // [N+1,96] bf16
    ushort* f1  = xb + (size_t)(N + 1) * 96;        // [N+1,64] bf16
    ushort* f2  = f1 + (size_t)(N + 1) * 64;        // [N2+1,64] bf16
    ushort* Bp1 = f2 + (size_t)(N2 + 1) * 64;       // 27*96*64 bf16
    ushort* Bp2 = Bp1 + 27 * 96 * 64;               // 8*64*64
    ushort* Bp3 = Bp2 + 8 * 64 * 64;                // 27*64*64
    float* partials = (float*)(Bp3 + 27 * 64 * 64); // [BN_NB,128]
    float* affA = partials + (size_t)BN_NB * 128;   // [64]
    float* affB = affA + 64;                        // [64]
    float* out  = (float*)d_out;                    // [N2,64] fp32

    // sentinel zero rows + input conversion + weight packing
    zero_rows<<<1, 128, 0, stream>>>(xb + (size_t)N * 96, f1 + (size_t)N * 64,
                                     f2 + (size_t)N2 * 64);
    cvt_bf16<<<2048, 256, 0, stream>>>(x, xb, N * 96 / 4);
    pack_W<27, 96><<<(27 * 3 * 4 * 64 + 255) / 256, 256, 0, stream>>>(W1, Bp1);
    pack_W<8, 64><<<(8 * 2 * 4 * 64 + 255) / 256, 256, 0, stream>>>(W2, Bp2);
    pack_W<27, 64><<<(27 * 2 * 4 * 64 + 255) / 256, 256, 0, stream>>>(W3, Bp3);

    // conv1: k=27, 96->64, leaky
    sconv_dg<27, 96, true, false><<<(N + 63) / 64, 256, 0, stream>>>(
        xb, nmap1, Bp1, b1, f1, N);
    // conv2: k=8, 64->64, leaky (downsample)
    sconv_dg<8, 64, true, false><<<(N2 + 63) / 64, 256, 0, stream>>>(
        f1, nmap2, Bp2, b2, f2, N2);
    // batchnorm stats (two-stage, deterministic) + in-place affine
    bn_partial<<<BN_NB, 256, 0, stream>>>(f2, N2, partials);
    bn_finalize<<<1, 1024, 0, stream>>>(partials, N2, gamma, beta, scale, affA, affB);
    aff_apply<<<2048, 256, 0, stream>>>(f2, N2 * 8, affA, affB);
    // conv3: k=27, 64->64, fp32 out
    sconv_dg<27, 64, false, true><<<(N2 + 63) / 64, 256, 0, stream>>>(
        f2, nmap3, Bp3, b3, out, N2);
}

// Round 5
// 153.585 us; speedup vs baseline: 4.7950x; 1.0327x over previous
//
#include <hip/hip_runtime.h>
#include <cstdint>

typedef __attribute__((ext_vector_type(8))) short bf16x8;
typedef __attribute__((ext_vector_type(4))) float f32x4;

#define BN_NB 256
#define LRELU_SLOPE 0.1f

__device__ __forceinline__ float bf2f(ushort h) {
    union { uint u; float v; } x; x.u = ((uint)h) << 16; return x.v;
}
__device__ __forceinline__ ushort f2bf(float f) {
    union { float v; uint u; } x; x.v = f;
    const uint r = (x.u + 0x7FFFu + ((x.u >> 16) & 1u)) >> 16;  // RNE
    return (ushort)r;
}

// m204 bijective XCD swizzle: contiguous grid chunk per XCD (8 XCDs).
__device__ __forceinline__ int xcd_swizzle(int bid, int nwg) {
    const int q = nwg >> 3, r = nwg & 7;
    const int xcd = bid & 7, local = bid >> 3;
    return (xcd < r ? xcd * (q + 1) : r * (q + 1) + (xcd - r) * q) + local;
}

// ---------------------------------------------------------------------------
// x (fp32) -> bf16, vectorized
// ---------------------------------------------------------------------------
__global__ __launch_bounds__(256) void cvt_bf16(const float* __restrict__ in,
                                                ushort* __restrict__ out, int n4)
{
    for (int i = blockIdx.x * 256 + threadIdx.x; i < n4; i += gridDim.x * 256) {
        const float4 v = reinterpret_cast<const float4*>(in)[i];
        ushort4 o;
        o.x = f2bf(v.x); o.y = f2bf(v.y); o.z = f2bf(v.z); o.w = f2bf(v.w);
        reinterpret_cast<ushort4*>(out)[i] = o;
    }
}

// ---------------------------------------------------------------------------
// Zero the sentinel rows appended to each feature table.
// ---------------------------------------------------------------------------
__global__ __launch_bounds__(128) void zero_rows(ushort* __restrict__ xbz,
                                                 ushort* __restrict__ f1z,
                                                 ushort* __restrict__ f2z)
{
    const int t = threadIdx.x;
    if (t < 96) xbz[t] = 0;
    if (t < 64) { f1z[t] = 0; f2z[t] = 0; }
}

// ---------------------------------------------------------------------------
// Pack W[K][CIN][64] fp32 -> bf16 B-fragments.
// Slice s = (tap*KB + kb)*4 + cb; lane l holds W[kb*32+(l>>4)*8+e][cb*16+(l&15)].
// ---------------------------------------------------------------------------
template<int K, int CIN>
__global__ __launch_bounds__(256) void pack_W(const float* __restrict__ W,
                                              ushort* __restrict__ Bp)
{
    constexpr int KB = CIN / 32;
    const int t = blockIdx.x * 256 + threadIdx.x;
    if (t >= K * KB * 4 * 64) return;
    const int l = t & 63;
    const int s = t >> 6;
    const int cb = s & 3;
    const int kk = s >> 2;
    const int kb = kk % KB;
    const int tap = kk / KB;
    const int k0 = kb * 32 + (l >> 4) * 8;
    const int col = cb * 16 + (l & 15);
    bf16x8 v;
#pragma unroll
    for (int e = 0; e < 8; ++e)
        v[e] = (short)f2bf(W[((size_t)tap * CIN + k0 + e) * 64 + col]);
    *reinterpret_cast<bf16x8*>(Bp + (size_t)t * 8) = v;
}

// ---------------------------------------------------------------------------
// Direct-gather sparse conv via MFMA 16x16x32 bf16, TAP-SPLIT across waves.
// Block: 256 thr = 4 waves, 32 output rows.
//   wave w: row-slice s = w&1 (rows s*16..s*16+15), tap-group g = w>>1
//   group 0: taps [0, T0), group 1: taps [T0, K); private accumulators,
//   merged via a conflict-free transposed LDS reduction at the end.
// Doubles grid (occupancy 35->~90%) and halves each wave's serial tap chain,
// with zero redundant gather traffic. No barriers in the tap loop.
// ---------------------------------------------------------------------------
template<int K, int CIN, bool LEAKY, bool OUTF32>
__global__ __launch_bounds__(256) void sconv_dg(
    const ushort* __restrict__ fin,      // [nin+1][CIN], row nin == zeros
    const int* __restrict__ nmap,        // [nout][K]
    const ushort* __restrict__ Bp,       // packed B fragments
    const float* __restrict__ bias,      // [64]
    void* __restrict__ fout, int nout)
{
    constexpr int KB = CIN / 32;
    constexpr int T0 = (K + 1) / 2;
    __shared__ int idxc[32 * K];
    __shared__ float redbuf[16 * 128];   // [acc elem j][slice*64 + lane]

    const int tid = threadIdx.x;
    const int l = tid & 63;
    const int w = tid >> 6;
    const int slice = w & 1;
    const int g = w >> 1;
    const int base = xcd_swizzle(blockIdx.x, gridDim.x) * 32;

    // cache this block's nmap rows (coalesced); OOB rows use row 0 (discarded)
    for (int e = tid; e < 32 * K; e += 256) {
        const int r = base + e / K;
        idxc[e] = (r < nout) ? nmap[(size_t)r * K + (e % K)] : 0;
    }
    __syncthreads();

    const int lrow = l & 15;
    const int grp = l >> 4;
    const int myrow = slice * 16 + lrow;      // row within block
    const int koff = grp * 8;                 // ushort offset inside a 32-k chunk

    const int kbeg = (g == 0) ? 0 : T0;
    const int kend = (g == 0) ? T0 : K;

    f32x4 acc[4];
#pragma unroll
    for (int cb = 0; cb < 4; ++cb) acc[cb] = (f32x4){0.f, 0.f, 0.f, 0.f};

    const bf16x8* __restrict__ B8 = reinterpret_cast<const bf16x8*>(Bp);

    bf16x8 a_cur[KB];
    {
        const size_t idx = (size_t)idxc[myrow * K + kbeg];
#pragma unroll
        for (int kb = 0; kb < KB; ++kb)
            a_cur[kb] = *reinterpret_cast<const bf16x8*>(fin + idx * CIN + kb * 32 + koff);
    }

    for (int k = kbeg; k < kend; ++k) {
        // prefetch next tap's A-fragments (clamped on last iter)
        const int kn = (k + 1 < kend) ? k + 1 : k;
        const size_t idxn = (size_t)idxc[myrow * K + kn];
        bf16x8 a_nxt[KB];
#pragma unroll
        for (int kb = 0; kb < KB; ++kb)
            a_nxt[kb] = *reinterpret_cast<const bf16x8*>(fin + idxn * CIN + kb * 32 + koff);

        const bf16x8* __restrict__ bk = B8 + (size_t)k * KB * 4 * 64 + l;
#pragma unroll
        for (int kb = 0; kb < KB; ++kb) {
#pragma unroll
            for (int cb = 0; cb < 4; ++cb)
                acc[cb] = __builtin_amdgcn_mfma_f32_16x16x32_bf16(
                    a_cur[kb], bk[(kb * 4 + cb) * 64], acc[cb], 0, 0, 0);
        }
#pragma unroll
        for (int kb = 0; kb < KB; ++kb) a_cur[kb] = a_nxt[kb];
    }

    // ---- merge tap-group partials (transposed layout: conflict-free) ----
    if (g == 1) {
#pragma unroll
        for (int cb = 0; cb < 4; ++cb)
#pragma unroll
            for (int i = 0; i < 4; ++i)
                redbuf[(cb * 4 + i) * 128 + slice * 64 + l] = acc[cb][i];
    }
    __syncthreads();
    if (g == 1) return;
#pragma unroll
    for (int cb = 0; cb < 4; ++cb)
#pragma unroll
        for (int i = 0; i < 4; ++i)
            acc[cb][i] += redbuf[(cb * 4 + i) * 128 + slice * 64 + l];

    // ---- epilogue: D row = grp*4+i, col = lrow (m89-verified) ----
    const int r0 = base + slice * 16 + grp * 4;
#pragma unroll
    for (int cb = 0; cb < 4; ++cb) {
        const int col = cb * 16 + lrow;
        const float bcol = bias[col];
#pragma unroll
        for (int i = 0; i < 4; ++i) {
            const int r = r0 + i;
            if (r < nout) {
                float o = acc[cb][i] + bcol;
                if (LEAKY) o = o >= 0.f ? o : LRELU_SLOPE * o;
                if (OUTF32) reinterpret_cast<float*>(fout)[(size_t)r * 64 + col] = o;
                else        reinterpret_cast<ushort*>(fout)[(size_t)r * 64 + col] = f2bf(o);
            }
        }
    }
}

// ---------------------------------------------------------------------------
// BatchNorm stage 1 (bf16 input): deterministic per-block partial sum/sumsq.
// ---------------------------------------------------------------------------
__global__ __launch_bounds__(256) void bn_partial(const ushort* __restrict__ f2v, int n2,
                                                  float* __restrict__ partials)
{
    const int c = threadIdx.x & 63;
    const int g = threadIdx.x >> 6;
    float s = 0.f, ss = 0.f;
    for (int r = blockIdx.x * 4 + g; r < n2; r += gridDim.x * 4) {
        const float v = bf2f(f2v[(size_t)r * 64 + c]);
        s += v;
        ss = fmaf(v, v, ss);
    }
    __shared__ float red[4][128];
    red[g][c] = s;
    red[g][64 + c] = ss;
    __syncthreads();
    if (g == 0) {
        partials[(size_t)blockIdx.x * 128 + c] =
            red[0][c] + red[1][c] + red[2][c] + red[3][c];
        partials[(size_t)blockIdx.x * 128 + 64 + c] =
            red[0][64 + c] + red[1][64 + c] + red[2][64 + c] + red[3][64 + c];
    }
}

// ---------------------------------------------------------------------------
// BatchNorm stage 2: PARALLEL final reduce (1024 thr = 8 row-groups x 128 cols)
// -> per-channel affine a,b with scale folded.
// ---------------------------------------------------------------------------
__global__ __launch_bounds__(1024) void bn_finalize(const float* __restrict__ partials, int n2,
                                                    const float* __restrict__ gamma,
                                                    const float* __restrict__ beta,
                                                    const float* __restrict__ scale,
                                                    float* __restrict__ affA, float* __restrict__ affB)
{
    const int t = threadIdx.x;
    const int col = t & 127;
    const int g = t >> 7;
    float s = 0.f;
#pragma unroll
    for (int b = g; b < BN_NB; b += 8)
        s += partials[(size_t)b * 128 + col];
    __shared__ float red[8][128];
    red[g][col] = s;
    __syncthreads();
    if (g == 0) {
        float S = red[0][col];
#pragma unroll
        for (int i = 1; i < 8; ++i) S += red[i][col];
        red[0][col] = S;
    }
    __syncthreads();
    if (t < 64) {
        const float S = red[0][t];
        const float SS = red[0][64 + t];
        const float inv_n = 1.f / (float)n2;
        const float mu = S * inv_n;
        const float var = fmaxf(SS * inv_n - mu * mu, 0.f);
        const float rs = rsqrtf(var + 1e-5f);
        const float sc = scale[0];
        const float ga = gamma[t];
        affA[t] = rs * ga * sc;
        affB[t] = (beta[t] - mu * rs * ga) * sc;
    }
}

// ---------------------------------------------------------------------------
// In-place BN affine on f2 (bf16): f2 = f2*a + b. Elementwise, deterministic.
// ---------------------------------------------------------------------------
__global__ __launch_bounds__(256) void aff_apply(ushort* __restrict__ f2, int nchunk,
                                                 const float* __restrict__ affA,
                                                 const float* __restrict__ affB)
{
    for (int i = blockIdx.x * 256 + threadIdx.x; i < nchunk; i += gridDim.x * 256) {
        const int c = i & 7;  // chunk-within-row
        bf16x8 v = *reinterpret_cast<const bf16x8*>(f2 + (size_t)i * 8);
#pragma unroll
        for (int j = 0; j < 8; ++j)
            v[j] = (short)f2bf(fmaf(bf2f((ushort)v[j]), affA[c * 8 + j], affB[c * 8 + j]));
        *reinterpret_cast<bf16x8*>(f2 + (size_t)i * 8) = v;
    }
}

extern "C" void kernel_launch(void* const* d_in, const int* in_sizes, int n_in,
                              void* d_out, int out_size, void* d_ws, size_t ws_size,
                              hipStream_t stream)
{
    const float* x     = (const float*)d_in[0];
    const float* W1    = (const float*)d_in[1];
    const float* b1    = (const float*)d_in[2];
    const float* W2    = (const float*)d_in[3];
    const float* b2    = (const float*)d_in[4];
    const float* W3    = (const float*)d_in[5];
    const float* b3    = (const float*)d_in[6];
    const float* gamma = (const float*)d_in[7];
    const float* beta  = (const float*)d_in[8];
    const float* scale = (const float*)d_in[9];
    const int* nmap1   = (const int*)d_in[10];
    const int* nmap2   = (const int*)d_in[11];
    const int* nmap3   = (const int*)d_in[12];

    const int N  = in_sizes[0] / 96;    // stride-1 points
    const int N2 = in_sizes[11] / 8;    // stride-2 points

    // workspace (all regions 16B-aligned; +1 zero row per feature table)
    ushort* xb  = (ushort*)d_ws;                    // [N+1,96] bf16
    ushort* f1  = xb + (size_t)(N + 1) * 96;        // [N+1,64] bf16
    ushort* f2  = f1 + (size_t)(N + 1) * 64;        // [N2+1,64] bf16
    ushort* Bp1 = f2 + (size_t)(N2 + 1) * 64;       // 27*96*64 bf16
    ushort* Bp2 = Bp1 + 27 * 96 * 64;               // 8*64*64
    ushort* Bp3 = Bp2 + 8 * 64 * 64;                // 27*64*64
    float* partials = (float*)(Bp3 + 27 * 64 * 64); // [BN_NB,128]
    float* affA = partials + (size_t)BN_NB * 128;   // [64]
    float* affB = affA + 64;                        // [64]
    float* out  = (float*)d_out;                    // [N2,64] fp32

    // sentinel zero rows + input conversion + weight packing
    zero_rows<<<1, 128, 0, stream>>>(xb + (size_t)N * 96, f1 + (size_t)N * 64,
                                     f2 + (size_t)N2 * 64);
    cvt_bf16<<<2048, 256, 0, stream>>>(x, xb, N * 96 / 4);
    pack_W<27, 96><<<(27 * 3 * 4 * 64 + 255) / 256, 256, 0, stream>>>(W1, Bp1);
    pack_W<8, 64><<<(8 * 2 * 4 * 64 + 255) / 256, 256, 0, stream>>>(W2, Bp2);
    pack_W<27, 64><<<(27 * 2 * 4 * 64 + 255) / 256, 256, 0, stream>>>(W3, Bp3);

    // conv1: k=27, 96->64, leaky
    sconv_dg<27, 96, true, false><<<(N + 31) / 32, 256, 0, stream>>>(
        xb, nmap1, Bp1, b1, f1, N);
    // conv2: k=8, 64->64, leaky (downsample)
    sconv_dg<8, 64, true, false><<<(N2 + 31) / 32, 256, 0, stream>>>(
        f1, nmap2, Bp2, b2, f2, N2);
    // batchnorm stats (two-stage, deterministic) + in-place affine
    bn_partial<<<BN_NB, 256, 0, stream>>>(f2, N2, partials);
    bn_finalize<<<1, 1024, 0, stream>>>(partials, N2, gamma, beta, scale, affA, affB);
    aff_apply<<<2048, 256, 0, stream>>>(f2, N2 * 8, affA, affB);
    // conv3: k=27, 64->64, fp32 out
    sconv_dg<27, 64, false, true><<<(N2 + 31) / 32, 256, 0, stream>>>(
        f2, nmap3, Bp3, b3, out, N2);
}

// Round 6
// 148.572 us; speedup vs baseline: 4.9568x; 1.0337x over previous
//
#include <hip/hip_runtime.h>
#include <cstdint>

typedef __attribute__((ext_vector_type(8))) short bf16x8;
typedef __attribute__((ext_vector_type(4))) float f32x4;

#define BN_NB 256
#define LRELU_SLOPE 0.1f

__device__ __forceinline__ float bf2f(ushort h) {
    union { uint u; float v; } x; x.u = ((uint)h) << 16; return x.v;
}
__device__ __forceinline__ ushort f2bf(float f) {
    union { float v; uint u; } x; x.v = f;
    const uint r = (x.u + 0x7FFFu + ((x.u >> 16) & 1u)) >> 16;  // RNE
    return (ushort)r;
}

// m204 bijective XCD swizzle: contiguous grid chunk per XCD (8 XCDs).
__device__ __forceinline__ int xcd_swizzle(int bid, int nwg) {
    const int q = nwg >> 3, r = nwg & 7;
    const int xcd = bid & 7, local = bid >> 3;
    return (xcd < r ? xcd * (q + 1) : r * (q + 1) + (xcd - r) * q) + local;
}

// ---------------------------------------------------------------------------
// x (fp32) -> bf16, vectorized
// ---------------------------------------------------------------------------
__global__ __launch_bounds__(256) void cvt_bf16(const float* __restrict__ in,
                                                ushort* __restrict__ out, int n4)
{
    for (int i = blockIdx.x * 256 + threadIdx.x; i < n4; i += gridDim.x * 256) {
        const float4 v = reinterpret_cast<const float4*>(in)[i];
        ushort4 o;
        o.x = f2bf(v.x); o.y = f2bf(v.y); o.z = f2bf(v.z); o.w = f2bf(v.w);
        reinterpret_cast<ushort4*>(out)[i] = o;
    }
}

// ---------------------------------------------------------------------------
// Zero the sentinel rows appended to each feature table.
// ---------------------------------------------------------------------------
__global__ __launch_bounds__(128) void zero_rows(ushort* __restrict__ xbz,
                                                 ushort* __restrict__ f1z,
                                                 ushort* __restrict__ f2z)
{
    const int t = threadIdx.x;
    if (t < 96) xbz[t] = 0;
    if (t < 64) { f1z[t] = 0; f2z[t] = 0; }
}

// ---------------------------------------------------------------------------
// Pack W[K][CIN][64] fp32 -> bf16 B-fragments.
// Slice s = (tap*KB + kb)*4 + cb; lane l holds W[kb*32+(l>>4)*8+e][cb*16+(l&15)].
// ---------------------------------------------------------------------------
template<int K, int CIN>
__global__ __launch_bounds__(256) void pack_W(const float* __restrict__ W,
                                              ushort* __restrict__ Bp)
{
    constexpr int KB = CIN / 32;
    const int t = blockIdx.x * 256 + threadIdx.x;
    if (t >= K * KB * 4 * 64) return;
    const int l = t & 63;
    const int s = t >> 6;
    const int cb = s & 3;
    const int kk = s >> 2;
    const int kb = kk % KB;
    const int tap = kk / KB;
    const int k0 = kb * 32 + (l >> 4) * 8;
    const int col = cb * 16 + (l & 15);
    bf16x8 v;
#pragma unroll
    for (int e = 0; e < 8; ++e)
        v[e] = (short)f2bf(W[((size_t)tap * CIN + k0 + e) * 64 + col]);
    *reinterpret_cast<bf16x8*>(Bp + (size_t)t * 8) = v;
}

// ---------------------------------------------------------------------------
// Direct-gather sparse conv via MFMA 16x16x32 bf16, 32 ROWS PER WAVE.
// Block: 128 thr = 2 waves, 64 output rows; wave w: rows w*32..w*32+31.
// Each wave holds 2 row-group A-fragments and loads each B-fragment ONCE per
// tap, feeding both row-groups' MFMAs -> halves B traffic + B VMEM instrs
// per output row vs 16-row waves; 24 MFMA per tap-round covers the
// prefetched next-tap gather latency. No barriers in the tap loop.
// Sentinel rows -> appended zero row. Grid is XCD-swizzled for L2 locality.
// ---------------------------------------------------------------------------
template<int K, int CIN, bool LEAKY, bool OUTF32>
__global__ __launch_bounds__(128) void sconv_dg(
    const ushort* __restrict__ fin,      // [nin+1][CIN], row nin == zeros
    const int* __restrict__ nmap,        // [nout][K]
    const ushort* __restrict__ Bp,       // packed B fragments
    const float* __restrict__ bias,      // [64]
    void* __restrict__ fout, int nout)
{
    constexpr int KB = CIN / 32;
    __shared__ int idxc[64 * K];

    const int tid = threadIdx.x;
    const int l = tid & 63;
    const int w = tid >> 6;              // 0..1
    const int base = xcd_swizzle(blockIdx.x, gridDim.x) * 64;

    // cache this block's nmap rows (coalesced); OOB rows use row 0 (discarded)
    for (int e = tid; e < 64 * K; e += 128) {
        const int r = base + e / K;
        idxc[e] = (r < nout) ? nmap[(size_t)r * K + (e % K)] : 0;
    }
    __syncthreads();

    const int lrow = l & 15;
    const int grp = l >> 4;
    const int row0 = w * 32 + lrow;       // row-group 0 (within block)
    const int row1 = w * 32 + 16 + lrow;  // row-group 1
    const int koff = grp * 8;             // ushort offset inside a 32-k chunk

    f32x4 acc0[4], acc1[4];
#pragma unroll
    for (int cb = 0; cb < 4; ++cb) {
        acc0[cb] = (f32x4){0.f, 0.f, 0.f, 0.f};
        acc1[cb] = (f32x4){0.f, 0.f, 0.f, 0.f};
    }

    const bf16x8* __restrict__ B8 = reinterpret_cast<const bf16x8*>(Bp);

    bf16x8 a0_cur[KB], a1_cur[KB];
    {
        const size_t i0 = (size_t)idxc[row0 * K];
        const size_t i1 = (size_t)idxc[row1 * K];
#pragma unroll
        for (int kb = 0; kb < KB; ++kb) {
            a0_cur[kb] = *reinterpret_cast<const bf16x8*>(fin + i0 * CIN + kb * 32 + koff);
            a1_cur[kb] = *reinterpret_cast<const bf16x8*>(fin + i1 * CIN + kb * 32 + koff);
        }
    }

    for (int k = 0; k < K; ++k) {
        // prefetch next tap's A-fragments (clamped on last iter)
        const int kn = (k + 1 < K) ? k + 1 : k;
        const size_t i0 = (size_t)idxc[row0 * K + kn];
        const size_t i1 = (size_t)idxc[row1 * K + kn];
        bf16x8 a0_nxt[KB], a1_nxt[KB];
#pragma unroll
        for (int kb = 0; kb < KB; ++kb) {
            a0_nxt[kb] = *reinterpret_cast<const bf16x8*>(fin + i0 * CIN + kb * 32 + koff);
            a1_nxt[kb] = *reinterpret_cast<const bf16x8*>(fin + i1 * CIN + kb * 32 + koff);
        }

        const bf16x8* __restrict__ bk = B8 + (size_t)k * KB * 4 * 64 + l;
#pragma unroll
        for (int kb = 0; kb < KB; ++kb) {
#pragma unroll
            for (int cb = 0; cb < 4; ++cb) {
                const bf16x8 b = bk[(kb * 4 + cb) * 64];   // loaded once, used twice
                acc0[cb] = __builtin_amdgcn_mfma_f32_16x16x32_bf16(a0_cur[kb], b, acc0[cb], 0, 0, 0);
                acc1[cb] = __builtin_amdgcn_mfma_f32_16x16x32_bf16(a1_cur[kb], b, acc1[cb], 0, 0, 0);
            }
        }
#pragma unroll
        for (int kb = 0; kb < KB; ++kb) { a0_cur[kb] = a0_nxt[kb]; a1_cur[kb] = a1_nxt[kb]; }
    }

    // ---- epilogue: D row = grp*4+i, col = cb*16+lrow (m89-verified) ----
    const float4 bv = *reinterpret_cast<const float4*>(bias);  // dummy to keep bias in cache
    (void)bv;
#pragma unroll
    for (int rg = 0; rg < 2; ++rg) {
        const f32x4* acc = rg ? acc1 : acc0;
        const int r0 = base + w * 32 + rg * 16 + grp * 4;
#pragma unroll
        for (int cb = 0; cb < 4; ++cb) {
            const int col = cb * 16 + lrow;
            const float bcol = bias[col];
#pragma unroll
            for (int i = 0; i < 4; ++i) {
                const int r = r0 + i;
                if (r < nout) {
                    float o = acc[cb][i] + bcol;
                    if (LEAKY) o = o >= 0.f ? o : LRELU_SLOPE * o;
                    if (OUTF32) reinterpret_cast<float*>(fout)[(size_t)r * 64 + col] = o;
                    else        reinterpret_cast<ushort*>(fout)[(size_t)r * 64 + col] = f2bf(o);
                }
            }
        }
    }
}

// ---------------------------------------------------------------------------
// BatchNorm stage 1 (bf16 input): deterministic per-block partial sum/sumsq.
// ---------------------------------------------------------------------------
__global__ __launch_bounds__(256) void bn_partial(const ushort* __restrict__ f2v, int n2,
                                                  float* __restrict__ partials)
{
    const int c = threadIdx.x & 63;
    const int g = threadIdx.x >> 6;
    float s = 0.f, ss = 0.f;
    for (int r = blockIdx.x * 4 + g; r < n2; r += gridDim.x * 4) {
        const float v = bf2f(f2v[(size_t)r * 64 + c]);
        s += v;
        ss = fmaf(v, v, ss);
    }
    __shared__ float red[4][128];
    red[g][c] = s;
    red[g][64 + c] = ss;
    __syncthreads();
    if (g == 0) {
        partials[(size_t)blockIdx.x * 128 + c] =
            red[0][c] + red[1][c] + red[2][c] + red[3][c];
        partials[(size_t)blockIdx.x * 128 + 64 + c] =
            red[0][64 + c] + red[1][64 + c] + red[2][64 + c] + red[3][64 + c];
    }
}

// ---------------------------------------------------------------------------
// BatchNorm stage 2: PARALLEL final reduce (1024 thr = 8 row-groups x 128 cols)
// -> per-channel affine a,b with scale folded.
// ---------------------------------------------------------------------------
__global__ __launch_bounds__(1024) void bn_finalize(const float* __restrict__ partials, int n2,
                                                    const float* __restrict__ gamma,
                                                    const float* __restrict__ beta,
                                                    const float* __restrict__ scale,
                                                    float* __restrict__ affA, float* __restrict__ affB)
{
    const int t = threadIdx.x;
    const int col = t & 127;
    const int g = t >> 7;
    float s = 0.f;
#pragma unroll
    for (int b = g; b < BN_NB; b += 8)
        s += partials[(size_t)b * 128 + col];
    __shared__ float red[8][128];
    red[g][col] = s;
    __syncthreads();
    if (g == 0) {
        float S = red[0][col];
#pragma unroll
        for (int i = 1; i < 8; ++i) S += red[i][col];
        red[0][col] = S;
    }
    __syncthreads();
    if (t < 64) {
        const float S = red[0][t];
        const float SS = red[0][64 + t];
        const float inv_n = 1.f / (float)n2;
        const float mu = S * inv_n;
        const float var = fmaxf(SS * inv_n - mu * mu, 0.f);
        const float rs = rsqrtf(var + 1e-5f);
        const float sc = scale[0];
        const float ga = gamma[t];
        affA[t] = rs * ga * sc;
        affB[t] = (beta[t] - mu * rs * ga) * sc;
    }
}

// ---------------------------------------------------------------------------
// In-place BN affine on f2 (bf16): f2 = f2*a + b. Elementwise, deterministic.
// ---------------------------------------------------------------------------
__global__ __launch_bounds__(256) void aff_apply(ushort* __restrict__ f2, int nchunk,
                                                 const float* __restrict__ affA,
                                                 const float* __restrict__ affB)
{
    for (int i = blockIdx.x * 256 + threadIdx.x; i < nchunk; i += gridDim.x * 256) {
        const int c = i & 7;  // chunk-within-row
        bf16x8 v = *reinterpret_cast<const bf16x8*>(f2 + (size_t)i * 8);
#pragma unroll
        for (int j = 0; j < 8; ++j)
            v[j] = (short)f2bf(fmaf(bf2f((ushort)v[j]), affA[c * 8 + j], affB[c * 8 + j]));
        *reinterpret_cast<bf16x8*>(f2 + (size_t)i * 8) = v;
    }
}

extern "C" void kernel_launch(void* const* d_in, const int* in_sizes, int n_in,
                              void* d_out, int out_size, void* d_ws, size_t ws_size,
                              hipStream_t stream)
{
    const float* x     = (const float*)d_in[0];
    const float* W1    = (const float*)d_in[1];
    const float* b1    = (const float*)d_in[2];
    const float* W2    = (const float*)d_in[3];
    const float* b2    = (const float*)d_in[4];
    const float* W3    = (const float*)d_in[5];
    const float* b3    = (const float*)d_in[6];
    const float* gamma = (const float*)d_in[7];
    const float* beta  = (const float*)d_in[8];
    const float* scale = (const float*)d_in[9];
    const int* nmap1   = (const int*)d_in[10];
    const int* nmap2   = (const int*)d_in[11];
    const int* nmap3   = (const int*)d_in[12];

    const int N  = in_sizes[0] / 96;    // stride-1 points
    const int N2 = in_sizes[11] / 8;    // stride-2 points

    // workspace (all regions 16B-aligned; +1 zero row per feature table)
    ushort* xb  = (ushort*)d_ws;                    // [N+1,96] bf16
    ushort* f1  = xb + (size_t)(N + 1) * 96;        // [N+1,64] bf16
    ushort* f2  = f1 + (size_t)(N + 1) * 64;        // [N2+1,64] bf16
    ushort* Bp1 = f2 + (size_t)(N2 + 1) * 64;       // 27*96*64 bf16
    ushort* Bp2 = Bp1 + 27 * 96 * 64;               // 8*64*64
    ushort* Bp3 = Bp2 + 8 * 64 * 64;                // 27*64*64
    float* partials = (float*)(Bp3 + 27 * 64 * 64); // [BN_NB,128]
    float* affA = partials + (size_t)BN_NB * 128;   // [64]
    float* affB = affA + 64;                        // [64]
    float* out  = (float*)d_out;                    // [N2,64] fp32

    // sentinel zero rows + input conversion + weight packing
    zero_rows<<<1, 128, 0, stream>>>(xb + (size_t)N * 96, f1 + (size_t)N * 64,
                                     f2 + (size_t)N2 * 64);
    cvt_bf16<<<2048, 256, 0, stream>>>(x, xb, N * 96 / 4);
    pack_W<27, 96><<<(27 * 3 * 4 * 64 + 255) / 256, 256, 0, stream>>>(W1, Bp1);
    pack_W<8, 64><<<(8 * 2 * 4 * 64 + 255) / 256, 256, 0, stream>>>(W2, Bp2);
    pack_W<27, 64><<<(27 * 2 * 4 * 64 + 255) / 256, 256, 0, stream>>>(W3, Bp3);

    // conv1: k=27, 96->64, leaky
    sconv_dg<27, 96, true, false><<<(N + 63) / 64, 128, 0, stream>>>(
        xb, nmap1, Bp1, b1, f1, N);
    // conv2: k=8, 64->64, leaky (downsample)
    sconv_dg<8, 64, true, false><<<(N2 + 63) / 64, 128, 0, stream>>>(
        f1, nmap2, Bp2, b2, f2, N2);
    // batchnorm stats (two-stage, deterministic) + in-place affine
    bn_partial<<<BN_NB, 256, 0, stream>>>(f2, N2, partials);
    bn_finalize<<<1, 1024, 0, stream>>>(partials, N2, gamma, beta, scale, affA, affB);
    aff_apply<<<2048, 256, 0, stream>>>(f2, N2 * 8, affA, affB);
    // conv3: k=27, 64->64, fp32 out
    sconv_dg<27, 64, false, true><<<(N2 + 63) / 64, 128, 0, stream>>>(
        f2, nmap3, Bp3, b3, out, N2);
}

// Round 7
// 120.185 us; speedup vs baseline: 6.1276x; 1.2362x over previous
//
#include <hip/hip_runtime.h>
#include <cstdint>

typedef __attribute__((ext_vector_type(8))) short bf16x8;
typedef __attribute__((ext_vector_type(4))) float f32x4;

#define BN_NB 256
#define LRELU_SLOPE 0.1f

__device__ __forceinline__ float bf2f(ushort h) {
    union { uint u; float v; } x; x.u = ((uint)h) << 16; return x.v;
}
__device__ __forceinline__ ushort f2bf(float f) {
    union { float v; uint u; } x; x.v = f;
    const uint r = (x.u + 0x7FFFu + ((x.u >> 16) & 1u)) >> 16;  // RNE
    return (ushort)r;
}

// m204 bijective XCD swizzle: contiguous grid chunk per XCD (8 XCDs).
__device__ __forceinline__ int xcd_swizzle(int bid, int nwg) {
    const int q = nwg >> 3, r = nwg & 7;
    const int xcd = bid & 7, local = bid >> 3;
    return (xcd < r ? xcd * (q + 1) : r * (q + 1) + (xcd - r) * q) + local;
}

// async 16B global->LDS (wave-uniform LDS base + lane*16)
__device__ __forceinline__ void gload_lds16(const void* g, void* l) {
    __builtin_amdgcn_global_load_lds((const __attribute__((address_space(1))) void*)g,
                                     (__attribute__((address_space(3))) void*)l, 16, 0, 0);
}

// ---------------------------------------------------------------------------
// x (fp32) -> bf16, vectorized
// ---------------------------------------------------------------------------
__global__ __launch_bounds__(256) void cvt_bf16(const float* __restrict__ in,
                                                ushort* __restrict__ out, int n4)
{
    for (int i = blockIdx.x * 256 + threadIdx.x; i < n4; i += gridDim.x * 256) {
        const float4 v = reinterpret_cast<const float4*>(in)[i];
        ushort4 o;
        o.x = f2bf(v.x); o.y = f2bf(v.y); o.z = f2bf(v.z); o.w = f2bf(v.w);
        reinterpret_cast<ushort4*>(out)[i] = o;
    }
}

// ---------------------------------------------------------------------------
// Zero the sentinel rows appended to each feature table.
// ---------------------------------------------------------------------------
__global__ __launch_bounds__(128) void zero_rows(ushort* __restrict__ xbz,
                                                 ushort* __restrict__ f1z,
                                                 ushort* __restrict__ f2z)
{
    const int t = threadIdx.x;
    if (t < 96) xbz[t] = 0;
    if (t < 64) { f1z[t] = 0; f2z[t] = 0; }
}

// ---------------------------------------------------------------------------
// Pack W[K][CIN][64] fp32 -> bf16 B-fragments.
// Slice s = (tap*KB + kb)*4 + cb; lane l holds W[kb*32+(l>>4)*8+e][cb*16+(l&15)].
// ---------------------------------------------------------------------------
template<int K, int CIN>
__global__ __launch_bounds__(256) void pack_W(const float* __restrict__ W,
                                              ushort* __restrict__ Bp)
{
    constexpr int KB = CIN / 32;
    const int t = blockIdx.x * 256 + threadIdx.x;
    if (t >= K * KB * 4 * 64) return;
    const int l = t & 63;
    const int s = t >> 6;
    const int cb = s & 3;
    const int kk = s >> 2;
    const int kb = kk % KB;
    const int tap = kk / KB;
    const int k0 = kb * 32 + (l >> 4) * 8;
    const int col = cb * 16 + (l & 15);
    bf16x8 v;
#pragma unroll
    for (int e = 0; e < 8; ++e)
        v[e] = (short)f2bf(W[((size_t)tap * CIN + k0 + e) * 64 + col]);
    *reinterpret_cast<bf16x8*>(Bp + (size_t)t * 8) = v;
}

// ---------------------------------------------------------------------------
// Sparse conv via MFMA 16x16x32 bf16, B staged in LDS (double-buffered,
// global_load_lds) so B reads ride lgkmcnt while per-lane A-gathers ride
// vmcnt -- decoupled counters, A prefetched 1 tap ahead (unroll-2, no
// register copies). One __syncthreads per tap round.
// Block: 256 thr = 4 waves, 64 output rows; wave w: rows w*16..+15 x 64 cols.
// Sentinel rows -> appended zero row. Grid XCD-swizzled for L2 locality.
// ---------------------------------------------------------------------------
template<int K, int CIN, bool LEAKY, bool OUTF32>
__global__ __launch_bounds__(256) void sconv_dg(
    const ushort* __restrict__ fin,      // [nin+1][CIN], row nin == zeros
    const int* __restrict__ nmap,        // [nout][K]
    const ushort* __restrict__ Bp,       // packed B fragments
    const float* __restrict__ bias,      // [64]
    void* __restrict__ fout, int nout)
{
    constexpr int KB = CIN / 32;       // 32-k blocks per tap
    constexpr int CHUNKS = KB * 4;     // 1KB fragment-chunks per tap slice
    __shared__ int idxc[64 * K];
    __shared__ ushort Bbuf[2][CHUNKS * 512];

    const int tid = threadIdx.x;
    const int l = tid & 63;
    const int w = tid >> 6;            // 0..3
    const int base = xcd_swizzle(blockIdx.x, gridDim.x) * 64;

    // cache this block's nmap rows (coalesced); OOB rows use row 0 (discarded)
    for (int e = tid; e < 64 * K; e += 256) {
        const int r = base + e / K;
        idxc[e] = (r < nout) ? nmap[(size_t)r * K + (e % K)] : 0;
    }
    __syncthreads();

    const int lrow = l & 15;
    const int grp = l >> 4;
    const int myrow = w * 16 + lrow;
    const int koff = grp * 8;          // ushort offset inside a 32-k chunk

    f32x4 acc[4];
#pragma unroll
    for (int cb = 0; cb < 4; ++cb) acc[cb] = (f32x4){0.f, 0.f, 0.f, 0.f};

    // ---- helpers (macros keep all indexing compile-time static) ----
#define STAGE_B(tap, buf)                                                    \
    {                                                                        \
        _Pragma("unroll")                                                    \
        for (int j = 0; j < KB; ++j) {                                       \
            const int c = w * KB + j;                                        \
            gload_lds16(Bp + (size_t)(tap) * CHUNKS * 512 + c * 512 + l * 8, \
                        &Bbuf[buf][c * 512]);                                \
        }                                                                    \
    }

#define GATHER_A(SET, tap)                                                   \
    {                                                                        \
        const size_t idx_ = (size_t)idxc[myrow * K + (tap)];                 \
        const ushort* rp_ = fin + idx_ * CIN + koff;                         \
        _Pragma("unroll")                                                    \
        for (int kb = 0; kb < KB; ++kb)                                      \
            SET[kb] = *reinterpret_cast<const bf16x8*>(rp_ + kb * 32);       \
    }

#define COMPUTE(SET, buf)                                                    \
    {                                                                        \
        _Pragma("unroll")                                                    \
        for (int kb = 0; kb < KB; ++kb) {                                    \
            _Pragma("unroll")                                                \
            for (int cb = 0; cb < 4; ++cb) {                                 \
                const bf16x8 b_ = *reinterpret_cast<const bf16x8*>(          \
                    &Bbuf[buf][(kb * 4 + cb) * 512 + l * 8]);                \
                acc[cb] = __builtin_amdgcn_mfma_f32_16x16x32_bf16(           \
                    SET[kb], b_, acc[cb], 0, 0, 0);                          \
            }                                                                \
        }                                                                    \
    }

    bf16x8 aA[KB], aB[KB];
    STAGE_B(0, 0);
    GATHER_A(aA, 0);
    __syncthreads();   // buf0 staged (vmcnt(0) + barrier), aA resident

    for (int kp = 0; kp < K; kp += 2) {
        // round kp: compute from buf (kp&1)=0, stage kp+1 into buf 1
        if (kp + 1 < K) { STAGE_B(kp + 1, 1); GATHER_A(aB, kp + 1); }
        COMPUTE(aA, 0);
        __syncthreads();
        if (kp + 1 < K) {
            // round kp+1: compute from buf 1, stage kp+2 into buf 0
            if (kp + 2 < K) { STAGE_B(kp + 2, 0); GATHER_A(aA, kp + 2); }
            COMPUTE(aB, 1);
            __syncthreads();
        }
    }
#undef STAGE_B
#undef GATHER_A
#undef COMPUTE

    // ---- epilogue: D row = grp*4+i, col = cb*16+lrow (m89-verified) ----
    const int r0 = base + w * 16 + grp * 4;
#pragma unroll
    for (int cb = 0; cb < 4; ++cb) {
        const int col = cb * 16 + lrow;
        const float bcol = bias[col];
#pragma unroll
        for (int i = 0; i < 4; ++i) {
            const int r = r0 + i;
            if (r < nout) {
                float o = acc[cb][i] + bcol;
                if (LEAKY) o = o >= 0.f ? o : LRELU_SLOPE * o;
                if (OUTF32) reinterpret_cast<float*>(fout)[(size_t)r * 64 + col] = o;
                else        reinterpret_cast<ushort*>(fout)[(size_t)r * 64 + col] = f2bf(o);
            }
        }
    }
}

// ---------------------------------------------------------------------------
// BatchNorm stage 1 (bf16 input): deterministic per-block partial sum/sumsq.
// ---------------------------------------------------------------------------
__global__ __launch_bounds__(256) void bn_partial(const ushort* __restrict__ f2v, int n2,
                                                  float* __restrict__ partials)
{
    const int c = threadIdx.x & 63;
    const int g = threadIdx.x >> 6;
    float s = 0.f, ss = 0.f;
    for (int r = blockIdx.x * 4 + g; r < n2; r += gridDim.x * 4) {
        const float v = bf2f(f2v[(size_t)r * 64 + c]);
        s += v;
        ss = fmaf(v, v, ss);
    }
    __shared__ float red[4][128];
    red[g][c] = s;
    red[g][64 + c] = ss;
    __syncthreads();
    if (g == 0) {
        partials[(size_t)blockIdx.x * 128 + c] =
            red[0][c] + red[1][c] + red[2][c] + red[3][c];
        partials[(size_t)blockIdx.x * 128 + 64 + c] =
            red[0][64 + c] + red[1][64 + c] + red[2][64 + c] + red[3][64 + c];
    }
}

// ---------------------------------------------------------------------------
// BatchNorm stage 2: PARALLEL final reduce (1024 thr = 8 row-groups x 128 cols)
// -> per-channel affine a,b with scale folded.
// ---------------------------------------------------------------------------
__global__ __launch_bounds__(1024) void bn_finalize(const float* __restrict__ partials, int n2,
                                                    const float* __restrict__ gamma,
                                                    const float* __restrict__ beta,
                                                    const float* __restrict__ scale,
                                                    float* __restrict__ affA, float* __restrict__ affB)
{
    const int t = threadIdx.x;
    const int col = t & 127;
    const int g = t >> 7;
    float s = 0.f;
#pragma unroll
    for (int b = g; b < BN_NB; b += 8)
        s += partials[(size_t)b * 128 + col];
    __shared__ float red[8][128];
    red[g][col] = s;
    __syncthreads();
    if (g == 0) {
        float S = red[0][col];
#pragma unroll
        for (int i = 1; i < 8; ++i) S += red[i][col];
        red[0][col] = S;
    }
    __syncthreads();
    if (t < 64) {
        const float S = red[0][t];
        const float SS = red[0][64 + t];
        const float inv_n = 1.f / (float)n2;
        const float mu = S * inv_n;
        const float var = fmaxf(SS * inv_n - mu * mu, 0.f);
        const float rs = rsqrtf(var + 1e-5f);
        const float sc = scale[0];
        const float ga = gamma[t];
        affA[t] = rs * ga * sc;
        affB[t] = (beta[t] - mu * rs * ga) * sc;
    }
}

// ---------------------------------------------------------------------------
// In-place BN affine on f2 (bf16): f2 = f2*a + b. Elementwise, deterministic.
// ---------------------------------------------------------------------------
__global__ __launch_bounds__(256) void aff_apply(ushort* __restrict__ f2, int nchunk,
                                                 const float* __restrict__ affA,
                                                 const float* __restrict__ affB)
{
    for (int i = blockIdx.x * 256 + threadIdx.x; i < nchunk; i += gridDim.x * 256) {
        const int c = i & 7;  // chunk-within-row
        bf16x8 v = *reinterpret_cast<const bf16x8*>(f2 + (size_t)i * 8);
#pragma unroll
        for (int j = 0; j < 8; ++j)
            v[j] = (short)f2bf(fmaf(bf2f((ushort)v[j]), affA[c * 8 + j], affB[c * 8 + j]));
        *reinterpret_cast<bf16x8*>(f2 + (size_t)i * 8) = v;
    }
}

extern "C" void kernel_launch(void* const* d_in, const int* in_sizes, int n_in,
                              void* d_out, int out_size, void* d_ws, size_t ws_size,
                              hipStream_t stream)
{
    const float* x     = (const float*)d_in[0];
    const float* W1    = (const float*)d_in[1];
    const float* b1    = (const float*)d_in[2];
    const float* W2    = (const float*)d_in[3];
    const float* b2    = (const float*)d_in[4];
    const float* W3    = (const float*)d_in[5];
    const float* b3    = (const float*)d_in[6];
    const float* gamma = (const float*)d_in[7];
    const float* beta  = (const float*)d_in[8];
    const float* scale = (const float*)d_in[9];
    const int* nmap1   = (const int*)d_in[10];
    const int* nmap2   = (const int*)d_in[11];
    const int* nmap3   = (const int*)d_in[12];

    const int N  = in_sizes[0] / 96;    // stride-1 points
    const int N2 = in_sizes[11] / 8;    // stride-2 points

    // workspace (all regions 16B-aligned; +1 zero row per feature table)
    ushort* xb  = (ushort*)d_ws;                    // [N+1,96] bf16
    ushort* f1  = xb + (size_t)(N + 1) * 96;        // [N+1,64] bf16
    ushort* f2  = f1 + (size_t)(N + 1) * 64;        // [N2+1,64] bf16
    ushort* Bp1 = f2 + (size_t)(N2 + 1) * 64;       // 27*96*64 bf16
    ushort* Bp2 = Bp1 + 27 * 96 * 64;               // 8*64*64
    ushort* Bp3 = Bp2 + 8 * 64 * 64;                // 27*64*64
    float* partials = (float*)(Bp3 + 27 * 64 * 64); // [BN_NB,128]
    float* affA = partials + (size_t)BN_NB * 128;   // [64]
    float* affB = affA + 64;                        // [64]
    float* out  = (float*)d_out;                    // [N2,64] fp32

    // sentinel zero rows + input conversion + weight packing
    zero_rows<<<1, 128, 0, stream>>>(xb + (size_t)N * 96, f1 + (size_t)N * 64,
                                     f2 + (size_t)N2 * 64);
    cvt_bf16<<<2048, 256, 0, stream>>>(x, xb, N * 96 / 4);
    pack_W<27, 96><<<(27 * 3 * 4 * 64 + 255) / 256, 256, 0, stream>>>(W1, Bp1);
    pack_W<8, 64><<<(8 * 2 * 4 * 64 + 255) / 256, 256, 0, stream>>>(W2, Bp2);
    pack_W<27, 64><<<(27 * 2 * 4 * 64 + 255) / 256, 256, 0, stream>>>(W3, Bp3);

    // conv1: k=27, 96->64, leaky
    sconv_dg<27, 96, true, false><<<(N + 63) / 64, 256, 0, stream>>>(
        xb, nmap1, Bp1, b1, f1, N);
    // conv2: k=8, 64->64, leaky (downsample)
    sconv_dg<8, 64, true, false><<<(N2 + 63) / 64, 256, 0, stream>>>(
        f1, nmap2, Bp2, b2, f2, N2);
    // batchnorm stats (two-stage, deterministic) + in-place affine
    bn_partial<<<BN_NB, 256, 0, stream>>>(f2, N2, partials);
    bn_finalize<<<1, 1024, 0, stream>>>(partials, N2, gamma, beta, scale, affA, affB);
    aff_apply<<<2048, 256, 0, stream>>>(f2, N2 * 8, affA, affB);
    // conv3: k=27, 64->64, fp32 out
    sconv_dg<27, 64, false, true><<<(N2 + 63) / 64, 256, 0, stream>>>(
        f2, nmap3, Bp3, b3, out, N2);
}